// Round 4
// baseline (426.909 us; speedup 1.0000x reference)
//
#include <hip/hip_runtime.h>
#include <stdint.h>

typedef unsigned short u16;
typedef __bf16 bf16x8 __attribute__((ext_vector_type(8)));
typedef float f32x4 __attribute__((ext_vector_type(4)));
typedef unsigned short u16x4 __attribute__((ext_vector_type(4)));
typedef unsigned short u16x8 __attribute__((ext_vector_type(8)));

#define B_N   16
#define C_CH  128
#define O_CH  256
#define HW    56
#define PH    58
#define PW    72
#define NCG   16          // groups of 8 channels

#define GLOBAL_AS __attribute__((address_space(1)))
#define LDS_AS    __attribute__((address_space(3)))

__device__ __forceinline__ void glds16(const u16* g, u16* l) {
    __builtin_amdgcn_global_load_lds((const GLOBAL_AS void*)g, (LDS_AS void*)l, 16, 0, 0);
}

// ---------------------------------------------------------------------------
// prep1: quantize + pad + re-block NCHW -> xq[b][hp][cg][wp][c8] (bf16 bits).
// A (cg-octet, wp-run) is contiguous so the conv stages whole rows with
// contiguous 1 KB glds16 segments. One block per (b,hp).
// ---------------------------------------------------------------------------
__global__ __launch_bounds__(256) void quant_pad(const float* __restrict__ x,
                                                 u16* __restrict__ xq) {
    __shared__ u16 Lt[C_CH][57];                 // [c][w], 57 slots vs bank conflicts
    const int hp = blockIdx.x;
    const int b = blockIdx.y;
    const int tid = threadIdx.x;
    const int h = hp - 1;
    const bool interior = (unsigned)h < HW;

    if (interior) {
        const float* xr = x + ((size_t)b * C_CH * HW + h) * HW;
        for (int i = 0; i < 7; ++i) {            // 1792 float4 units = 128c x 14
            int u = i * 256 + tid;
            int c = u / 14, w4 = u % 14;
            float4 v = *(const float4*)(xr + (size_t)c * (HW * HW) + w4 * 4);
            float q0 = fminf(fmaxf(rintf(v.x * 255.0f), 0.0f), 255.0f);
            float q1 = fminf(fmaxf(rintf(v.y * 255.0f), 0.0f), 255.0f);
            float q2 = fminf(fmaxf(rintf(v.z * 255.0f), 0.0f), 255.0f);
            float q3 = fminf(fmaxf(rintf(v.w * 255.0f), 0.0f), 255.0f);
            Lt[c][w4 * 4 + 0] = (u16)(__float_as_uint(q0) >> 16);
            Lt[c][w4 * 4 + 1] = (u16)(__float_as_uint(q1) >> 16);
            Lt[c][w4 * 4 + 2] = (u16)(__float_as_uint(q2) >> 16);
            Lt[c][w4 * 4 + 3] = (u16)(__float_as_uint(q3) >> 16);
        }
    }
    __syncthreads();
    u16* dst = xq + (size_t)(b * PH + hp) * (NCG * PW * 8);
    for (int j = 0; j < 9; ++j) {
        int u = j * 256 + tid;                   // 2304 u16x4 units
        int c8b = (u & 1) * 4;
        int wp = (u >> 1) % PW;
        int cg = u / (2 * PW);
        int w = wp - 1;
        u16x4 v = (u16x4){0, 0, 0, 0};
        if (interior && (unsigned)w < HW) {
#pragma unroll
            for (int e = 0; e < 4; ++e) v[e] = Lt[cg * 8 + c8b + e][w];
        }
        *(u16x4*)(dst + (size_t)u * 4) = v;
    }
}

// ---------------------------------------------------------------------------
// prep2: Bw[r][cg][o][c8] = bf16bits( pcilt[o][cg*8+c8][r][1] ),  r = kh*3+kw.
// ---------------------------------------------------------------------------
__global__ __launch_bounds__(256) void make_w(const float* __restrict__ pcilt,
                                              u16* __restrict__ Bw) {
    int u = blockIdx.x * 256 + threadIdx.x;      // 36864 u16x8 units
    int o = u & 255;
    int cg = (u >> 8) & 15;
    int r = u >> 12;
    const float* src = pcilt + ((size_t)(o * C_CH + cg * 8) * 9 + r) * 256 + 1;
    u16x8 v;
#pragma unroll
    for (int e = 0; e < 8; ++e)
        v[e] = (u16)(__float_as_uint(src[(size_t)e * (9 * 256)]) >> 16);
    *(u16x8*)(Bw + (size_t)u * 8) = v;
}

// ---------------------------------------------------------------------------
// conv as implicit GEMM, stage-once structure:
// Block = 128 o x 128 m (m = dh*64 + w). The block's FULL input footprint for
// one c-half (64 ch) and all 9 taps is 4 rows x 8 oct x 72 wp = 36 KB -> LDS.
// 2 phases (c-halves), 4 barriers total. All 9 taps read LDS directly
// (virtual im2col). Weights stream from L2 with one-tap-ahead VGPR prefetch.
// ---------------------------------------------------------------------------
__global__ __launch_bounds__(256) void conv_mfma(const u16* __restrict__ xq,
                                                 const u16* __restrict__ Bw,
                                                 const float* __restrict__ bias,
                                                 float* __restrict__ out) {
    __shared__ __align__(16) u16 Ld[4][8][PW][8];   // [row][oct][wp][c8]  36,864 B

    const int tid = threadIdx.x;
    const int o_blk = blockIdx.x * 128;
    const int h0 = blockIdx.y * 2;
    const int b = blockIdx.z;

    const int lane = tid & 63;
    const int wid = tid >> 6;
    const int wo = wid & 1;
    const int wm = wid >> 1;
    const int quad = lane >> 4;
    const int lrow = lane & 15;

    f32x4 acc[4][4];
#pragma unroll
    for (int i = 0; i < 4; i++)
#pragma unroll
        for (int j = 0; j < 4; j++) acc[i][j] = (f32x4){0.f, 0.f, 0.f, 0.f};

    // weight lane base: Bw element ((cgw*256 + o_blk + wo*64 + i*16 + lrow) * 8)
    const u16* wl = Bw + (size_t)(o_blk + wo * 64 + lrow) * 8;
    // staging: wave wid stages padded row (h0 + wid); 9216 B = 9 x 1 KB glds
    const u16* gsrc_row = xq + (size_t)((b * PH + h0 + wid) * NCG) * (PW * 8) + lane * 8;
    u16* ldst_row = &Ld[wid][0][0][0];

    for (int half = 0; half < 2; ++half) {
        __syncthreads();
        {
            const u16* gs = gsrc_row + half * 8 * (PW * 8);
#pragma unroll
            for (int k = 0; k < 9; ++k)
                glds16(gs + k * 512, ldst_row + k * 512);
        }
        __syncthreads();

        bf16x8 af[2][2][4];
#pragma unroll
        for (int s = 0; s < 2; ++s) {
            const size_t base = (size_t)((0 * 16 + half * 8 + s * 4 + quad) * 256) * 8;
#pragma unroll
            for (int i = 0; i < 4; ++i)
                af[0][s][i] = *(const bf16x8*)(wl + base + (size_t)i * 16 * 8);
        }

#pragma unroll
        for (int r = 0; r < 9; ++r) {
            if (r < 8) {
#pragma unroll
                for (int s = 0; s < 2; ++s) {
                    const size_t base = (size_t)(((r + 1) * 16 + half * 8 + s * 4 + quad) * 256) * 8;
#pragma unroll
                    for (int i = 0; i < 4; ++i)
                        af[(r + 1) & 1][s][i] = *(const bf16x8*)(wl + base + (size_t)i * 16 * 8);
                }
            }
            const int kh = r / 3, kw = r % 3;
#pragma unroll
            for (int s = 0; s < 2; ++s) {
                bf16x8 bfr[4];
#pragma unroll
                for (int j = 0; j < 4; ++j)
                    bfr[j] = *(const bf16x8*)&Ld[wm + kh][s * 4 + quad][kw + j * 16 + lrow][0];
#pragma unroll
                for (int i = 0; i < 4; ++i)
#pragma unroll
                    for (int j = 0; j < 4; ++j)
                        acc[i][j] = __builtin_amdgcn_mfma_f32_16x16x32_bf16(af[r & 1][s][i], bfr[j], acc[i][j], 0, 0, 0);
            }
        }
    }

    // ---- epilogue: D[row=o][col=m]; col = lane&15, row = quad*4 + reg ----
    const int hh = h0 + wm;
#pragma unroll
    for (int i = 0; i < 4; i++) {
        const int obase = o_blk + wo * 64 + i * 16 + quad * 4;
#pragma unroll
        for (int j = 0; j < 4; j++) {
            const int w = j * 16 + lrow;
            if (w < HW) {
#pragma unroll
                for (int rg = 0; rg < 4; ++rg) {
                    const int o = obase + rg;
                    out[(((size_t)b * O_CH + o) * HW + hh) * HW + w] = acc[i][j][rg] + bias[o];
                }
            }
        }
    }
}

extern "C" void kernel_launch(void* const* d_in, const int* in_sizes, int n_in,
                              void* d_out, int out_size, void* d_ws, size_t ws_size,
                              hipStream_t stream) {
    const float* x     = (const float*)d_in[0];
    const float* pcilt = (const float*)d_in[1];
    const float* bias  = (const float*)d_in[2];
    float* out = (float*)d_out;

    u16* xq = (u16*)d_ws;                                   // 16*58*16*72*8 u16 = 17.1 MB
    u16* Bw = xq + (size_t)B_N * PH * NCG * PW * 8;         // 9*16*256*8 u16  = 0.6 MB

    quant_pad<<<dim3(PH, B_N), 256, 0, stream>>>(x, xq);
    make_w<<<(9 * NCG * O_CH * 8) / (8 * 256), 256, 0, stream>>>(pcilt, Bw);
    conv_mfma<<<dim3(O_CH / 128, HW / 2, B_N), dim3(256), 0, stream>>>(xq, Bw, bias, out);
}

// Round 5
// 422.868 us; speedup vs baseline: 1.0096x; 1.0096x over previous
//
#include <hip/hip_runtime.h>
#include <stdint.h>

typedef unsigned short u16;
typedef __bf16 bf16x8 __attribute__((ext_vector_type(8)));
typedef float f32x4 __attribute__((ext_vector_type(4)));
typedef unsigned short u16x2 __attribute__((ext_vector_type(2)));
typedef unsigned short u16x4 __attribute__((ext_vector_type(4)));

#define B_N   16
#define C_CH  128
#define O_CH  256
#define HW    56
#define PH    58
#define PW    72
#define NCG   16          // groups of 8 channels

#define GLOBAL_AS __attribute__((address_space(1)))
#define LDS_AS    __attribute__((address_space(3)))

__device__ __forceinline__ void glds16(const u16* g, u16* l) {
    __builtin_amdgcn_global_load_lds((const GLOBAL_AS void*)g, (LDS_AS void*)l, 16, 0, 0);
}

// ---------------------------------------------------------------------------
// prep1: quantize + pad + re-block NCHW -> xq[b][hp][cg][wp][c8] (bf16 bits).
// ---------------------------------------------------------------------------
__global__ __launch_bounds__(256) void quant_pad(const float* __restrict__ x,
                                                 u16* __restrict__ xq) {
    __shared__ u16 Lt[C_CH][57];
    const int hp = blockIdx.x;
    const int b = blockIdx.y;
    const int tid = threadIdx.x;
    const int h = hp - 1;
    const bool interior = (unsigned)h < HW;

    if (interior) {
        const float* xr = x + ((size_t)b * C_CH * HW + h) * HW;
        for (int i = 0; i < 7; ++i) {            // 1792 float4 units = 128c x 14
            int u = i * 256 + tid;
            int c = u / 14, w4 = u % 14;
            float4 v = *(const float4*)(xr + (size_t)c * (HW * HW) + w4 * 4);
            float q0 = fminf(fmaxf(rintf(v.x * 255.0f), 0.0f), 255.0f);
            float q1 = fminf(fmaxf(rintf(v.y * 255.0f), 0.0f), 255.0f);
            float q2 = fminf(fmaxf(rintf(v.z * 255.0f), 0.0f), 255.0f);
            float q3 = fminf(fmaxf(rintf(v.w * 255.0f), 0.0f), 255.0f);
            Lt[c][w4 * 4 + 0] = (u16)(__float_as_uint(q0) >> 16);
            Lt[c][w4 * 4 + 1] = (u16)(__float_as_uint(q1) >> 16);
            Lt[c][w4 * 4 + 2] = (u16)(__float_as_uint(q2) >> 16);
            Lt[c][w4 * 4 + 3] = (u16)(__float_as_uint(q3) >> 16);
        }
    }
    __syncthreads();
    u16* dst = xq + (size_t)(b * PH + hp) * (NCG * PW * 8);
    for (int j = 0; j < 9; ++j) {
        int u = j * 256 + tid;                   // 2304 u16x4 units
        int c8b = (u & 1) * 4;
        int wp = (u >> 1) % PW;
        int cg = u / (2 * PW);
        int w = wp - 1;
        u16x4 v = (u16x4){0, 0, 0, 0};
        if (interior && (unsigned)w < HW) {
#pragma unroll
            for (int e = 0; e < 4; ++e) v[e] = Lt[cg * 8 + c8b + e][w];
        }
        *(u16x4*)(dst + (size_t)u * 4) = v;
    }
}

// ---------------------------------------------------------------------------
// prep2: Bw[r][cg][o][c8] = bf16bits( pcilt[o][cg*8+c8][r][1] ),  r = kh*3+kw.
// One thread per c8-PAIR: 576 blocks (4x R4 parallelism), coalesced 4 B stores.
// ---------------------------------------------------------------------------
__global__ __launch_bounds__(256) void make_w(const float* __restrict__ pcilt,
                                              u16* __restrict__ Bw) {
    int v = blockIdx.x * 256 + threadIdx.x;      // 147456 units
    int e2 = v & 3;                              // c8 pair: channels e2*2, e2*2+1
    int o  = (v >> 2) & 255;
    int cg = (v >> 10) & 15;
    int r  = v >> 14;
    const float* src = pcilt + ((size_t)(o * C_CH + cg * 8 + e2 * 2) * 9 + r) * 256 + 1;
    u16x2 out2;
    out2[0] = (u16)(__float_as_uint(src[0]) >> 16);
    out2[1] = (u16)(__float_as_uint(src[(size_t)9 * 256]) >> 16);
    *(u16x2*)(Bw + (size_t)v * 2) = out2;        // unit index v == ((r*16+cg)*256+o)*4+e2
}

// ---------------------------------------------------------------------------
// conv as implicit GEMM, phase-double-buffered:
// Block = 128 o x 128 m (m = 2 h-rows x 64 w), 4 waves 2x2 (wo x wm).
// 4 phases of 4 c-octets (K=32 each). Ld[2] buffers (2 x 18 KB): phase q+1's
// glds16 issue right after the barrier and fly UNDER phase q's 144-MFMA
// compute, so the next barrier's vmcnt(0) drain is ~free. Weights stream
// direct from L2 with one-tap-ahead VGPR prefetch (af ping-pong, 32 VGPR).
// ---------------------------------------------------------------------------
__global__ __launch_bounds__(256, 3) void conv_mfma(const u16* __restrict__ xq,
                                                    const u16* __restrict__ Bw,
                                                    const float* __restrict__ bias,
                                                    float* __restrict__ out) {
    __shared__ __align__(16) u16 Ld[2][4][4][PW][8];   // [buf][row][oct][wp][c8] 36 KB

    const int tid = threadIdx.x;
    const int o_blk = blockIdx.x * 128;
    const int h0 = blockIdx.y * 2;
    const int b = blockIdx.z;

    const int lane = tid & 63;
    const int wid = tid >> 6;
    const int wo = wid & 1;
    const int wm = wid >> 1;
    const int quad = lane >> 4;
    const int lrow = lane & 15;

    f32x4 acc[4][4];
#pragma unroll
    for (int i = 0; i < 4; i++)
#pragma unroll
        for (int j = 0; j < 4; j++) acc[i][j] = (f32x4){0.f, 0.f, 0.f, 0.f};

    // weight lane base: Bw element ((cgw*256 + o_blk + wo*64 + i*16 + lrow)*8)
    const u16* wl = Bw + (size_t)(o_blk + wo * 64 + lrow) * 8;
    // staging source: wave wid stages padded row (h0 + wid); per phase 4 octs,
    // each oct-row = 1152 B covered by two overlapping 1 KB glds16.
    const u16* gsrow = xq + ((size_t)((b * PH + h0 + wid) * NCG) * PW) * 8 + lane * 8;

#define STAGE(q, t)                                                         \
    {                                                                       \
        const u16* gs = gsrow + (size_t)((q) * 4) * (PW * 8);               \
        u16* ld = &Ld[t][wid][0][0][0];                                     \
        _Pragma("unroll")                                                   \
        for (int oo = 0; oo < 4; ++oo) {                                    \
            glds16(gs + oo * 576, ld + oo * 576);                           \
            glds16(gs + oo * 576 + 64, ld + oo * 576 + 64);                 \
        }                                                                   \
    }

#define LOAD_AF(slot, q, r)                                                 \
    {                                                                       \
        const size_t base = (size_t)(((r) * 16 + (q) * 4 + quad) * 256) * 8;\
        _Pragma("unroll")                                                   \
        for (int i = 0; i < 4; ++i)                                         \
            af[slot][i] = *(const bf16x8*)(wl + base + (size_t)i * 16 * 8); \
    }

    STAGE(0, 0);
    bf16x8 af[2][4];

#pragma unroll
    for (int q = 0; q < 4; ++q) {
        const int t = q & 1;
        __syncthreads();                 // buf t staged; buf t^1 free
        if (q < 3) STAGE(q + 1, t ^ 1);  // fly under this phase's compute
        LOAD_AF(0, q, 0);
#pragma unroll
        for (int r = 0; r < 9; ++r) {
            if (r < 8) LOAD_AF((r + 1) & 1, q, r + 1);
            const int kh = r / 3, kw = r % 3;
            bf16x8 bfr[4];
#pragma unroll
            for (int j = 0; j < 4; ++j)
                bfr[j] = *(const bf16x8*)&Ld[t][wm + kh][quad][kw + j * 16 + lrow][0];
#pragma unroll
            for (int i = 0; i < 4; ++i)
#pragma unroll
                for (int j = 0; j < 4; ++j)
                    acc[i][j] = __builtin_amdgcn_mfma_f32_16x16x32_bf16(af[r & 1][i], bfr[j], acc[i][j], 0, 0, 0);
        }
    }

    // ---- epilogue: D[row=o][col=m]; col = lane&15, row = quad*4 + reg ----
    const int hh = h0 + wm;
#pragma unroll
    for (int i = 0; i < 4; i++) {
        const int obase = o_blk + wo * 64 + i * 16 + quad * 4;
#pragma unroll
        for (int j = 0; j < 4; j++) {
            const int w = j * 16 + lrow;
            if (w < HW) {
#pragma unroll
                for (int rg = 0; rg < 4; ++rg) {
                    const int o = obase + rg;
                    out[(((size_t)b * O_CH + o) * HW + hh) * HW + w] = acc[i][j][rg] + bias[o];
                }
            }
        }
    }
}

extern "C" void kernel_launch(void* const* d_in, const int* in_sizes, int n_in,
                              void* d_out, int out_size, void* d_ws, size_t ws_size,
                              hipStream_t stream) {
    const float* x     = (const float*)d_in[0];
    const float* pcilt = (const float*)d_in[1];
    const float* bias  = (const float*)d_in[2];
    float* out = (float*)d_out;

    u16* xq = (u16*)d_ws;                                   // 16*58*16*72*8 u16 = 17.1 MB
    u16* Bw = xq + (size_t)B_N * PH * NCG * PW * 8;         // 9*16*256*8 u16  = 0.6 MB

    quant_pad<<<dim3(PH, B_N), 256, 0, stream>>>(x, xq);
    make_w<<<(9 * NCG * O_CH * 4) / 256, 256, 0, stream>>>(pcilt, Bw);
    conv_mfma<<<dim3(O_CH / 128, HW / 2, B_N), dim3(256), 0, stream>>>(xq, Bw, bias, out);
}

// Round 6
// 406.182 us; speedup vs baseline: 1.0510x; 1.0411x over previous
//
#include <hip/hip_runtime.h>
#include <stdint.h>

typedef unsigned char u8;
typedef unsigned short u16;
typedef int i32x4 __attribute__((ext_vector_type(4)));
typedef u8 u8x4 __attribute__((ext_vector_type(4)));

#define B_N   16
#define C_CH  128
#define O_CH  256
#define HW    56
#define PH    58
#define PW    72

#define GLOBAL_AS __attribute__((address_space(1)))
#define LDS_AS    __attribute__((address_space(3)))

__device__ __forceinline__ void glds16(const void* g, void* l) {
    __builtin_amdgcn_global_load_lds((const GLOBAL_AS void*)g, (LDS_AS void*)l, 16, 0, 0);
}

// ws layout (bytes)
#define XQ_OFF   0                       // u8 [16][58][8 cg][72 wp][16 c]  = 8,552,448
#define BW_OFF   8552448                 // u8 [18 st][256 o][64 c]         =   294,912
#define TC_OFF   (BW_OFF + 294912)       // int [16][58][72]                =   267,264
#define SA_OFF   (TC_OFF + 267264)       // int [16][56][64]                =   229,376
#define WS_OFF   (SA_OFF + 229376)       // int [256]

// ---------------------------------------------------------------------------
// prep1: quantize + pad + NCHW->[b][hp][cg][wp][c16] as SHIFTED i8 (q ^ 0x80
// == q-128 two's-complement; pad = 0x80 = -128). Also emits the channel-sum
// plane Tc[b][hp][wp] = sum_c (q-128) (pad rows/cols = -16384) and zeroes Wsum.
// ---------------------------------------------------------------------------
__global__ __launch_bounds__(256) void quant_pad(const float* __restrict__ x,
                                                 u8* __restrict__ xq,
                                                 int* __restrict__ Tc,
                                                 int* __restrict__ Wsum) {
    __shared__ u16 Lt[C_CH][57];                 // integer q in [0,255]
    const int hp = blockIdx.x;
    const int b = blockIdx.y;
    const int tid = threadIdx.x;
    const int h = hp - 1;
    const bool interior = (unsigned)h < HW;

    if (hp == 0 && b == 0 && tid < 256) Wsum[tid] = 0;   // runs before make_w launch

    if (interior) {
        const float* xr = x + ((size_t)b * C_CH * HW + h) * HW;
        for (int i = 0; i < 7; ++i) {            // 1792 float4 units = 128c x 14
            int u = i * 256 + tid;
            int c = u / 14, w4 = u % 14;
            float4 v = *(const float4*)(xr + (size_t)c * (HW * HW) + w4 * 4);
            Lt[c][w4 * 4 + 0] = (u16)(int)fminf(fmaxf(rintf(v.x * 255.0f), 0.0f), 255.0f);
            Lt[c][w4 * 4 + 1] = (u16)(int)fminf(fmaxf(rintf(v.y * 255.0f), 0.0f), 255.0f);
            Lt[c][w4 * 4 + 2] = (u16)(int)fminf(fmaxf(rintf(v.z * 255.0f), 0.0f), 255.0f);
            Lt[c][w4 * 4 + 3] = (u16)(int)fminf(fmaxf(rintf(v.w * 255.0f), 0.0f), 255.0f);
        }
    }
    __syncthreads();
    // write xq row for (b,hp): 8 cg x 72 wp x 16 c = 9216 B = 2304 dwords
    u8* dst = xq + (size_t)(b * PH + hp) * 9216;
    for (int j = 0; j < 9; ++j) {
        int u = j * 256 + tid;
        int d4 = u & 3;                          // dword within the 16 B c-group
        int wp = (u >> 2) % PW;
        int cg = u / (4 * PW);
        int w = wp - 1;
        u8x4 v;
        if (interior && (unsigned)w < HW) {
#pragma unroll
            for (int e = 0; e < 4; ++e)
                v[e] = (u8)Lt[cg * 16 + d4 * 4 + e][w] ^ 0x80;
        } else {
            v = (u8x4){0x80, 0x80, 0x80, 0x80};
        }
        *(u8x4*)(dst + (size_t)u * 4) = v;
    }
    // channel-sum plane
    if (tid < PW) {
        int wp = tid, w = wp - 1;
        int s = -128 * C_CH;
        if (interior && (unsigned)w < HW) {
            for (int c = 0; c < C_CH; ++c) s += (int)Lt[c][w];
        }
        Tc[(b * PH + hp) * PW + wp] = s;
    }
}

// ---------------------------------------------------------------------------
// prep2 (fused): blocks [0,288): Bw[st=r*2+q][o][c64] = (u8)qw ^ 0x80, plus
// Wsum[o] += sum(qw-128) via 16-lane shuffle + atomics.
// blocks [288,484): Sa[b][h][w] = 3x3 box sum of Tc (the activation zero-point
// correction per output pixel).
// ---------------------------------------------------------------------------
__global__ __launch_bounds__(256) void make_w(const float* __restrict__ pcilt,
                                              u8* __restrict__ Bw,
                                              const int* __restrict__ Tc,
                                              int* __restrict__ Sa,
                                              int* __restrict__ Wsum) {
    const int bx = blockIdx.x;
    const int tid = threadIdx.x;
    if (bx < 288) {
        int v = bx * 256 + tid;                  // 73728 dword units
        int cb4 = v & 15;                        // dword within 64-c chunk
        int o   = (v >> 4) & 255;
        int q   = (v >> 12) & 1;
        int r   = v >> 13;
        u8x4 out4;
        int part = 0;
#pragma unroll
        for (int e = 0; e < 4; ++e) {
            int c = q * 64 + cb4 * 4 + e;
            float w = pcilt[((size_t)(o * C_CH + c) * 9 + r) * 256 + 1];
            int qi = (int)w;
            out4[e] = (u8)qi ^ 0x80;
            part += qi - 128;
        }
        *(u8x4*)(Bw + (size_t)v * 4) = out4;
        // reduce over the 16 lanes sharing o (lane&15 groups)
        part += __shfl_down(part, 1);
        part += __shfl_down(part, 2);
        part += __shfl_down(part, 4);
        part += __shfl_down(part, 8);
        if ((tid & 15) == 0) atomicAdd(&Wsum[o], part);
    } else {
        int sidx = (bx - 288) * 256 + tid;       // 50176 = 16*56*56
        int w = sidx % HW;
        int h = (sidx / HW) % HW;
        int b = sidx / (HW * HW);
        const int* t = Tc + (b * PH + h) * PW + w;   // hp = h+dh, wp = w+dw
        int s = 0;
#pragma unroll
        for (int dh = 0; dh < 3; ++dh)
#pragma unroll
            for (int dw = 0; dw < 3; ++dw)
                s += t[dh * PW + dw];
        Sa[(b * HW + h) * 64 + w] = s;
    }
}

// ---------------------------------------------------------------------------
// conv as implicit GEMM, exact i8 (zero-point shifted):
//   ACC[o][m] = sum_k (w-128)(a-128);  out = ACC + 128*Sa[m] + 128*Wsum[o]
//              + 128^2*1152, then + bias. 18 stages of K=64 (fine-grained
//              R3-winner structure), Is = 8 KB LDS, weights direct from L2.
// MFMA i32 16x16x64: A[m=lane&15][k=quad*16+idx], C/D col=lane&15,row=quad*4+reg.
// ---------------------------------------------------------------------------
__global__ __launch_bounds__(256) void conv_mfma(const u8* __restrict__ xq,
                                                 const u8* __restrict__ Bw,
                                                 const int* __restrict__ Sa,
                                                 const int* __restrict__ Wsum,
                                                 const float* __restrict__ bias,
                                                 float* __restrict__ out) {
    __shared__ __align__(16) u8 Is[4][128][16];   // [cg16][m][c16]  8 KB

    const int tid = threadIdx.x;
    const int o_blk = blockIdx.x * 128;
    const int h0 = blockIdx.y * 2;
    const int b = blockIdx.z;

    const int lane = tid & 63;
    const int wid = tid >> 6;
    const int wo = wid & 1;
    const int wm = wid >> 1;
    const int quad = lane >> 4;
    const int lrow = lane & 15;

    i32x4 acc[4][4];
#pragma unroll
    for (int i = 0; i < 4; i++)
#pragma unroll
        for (int j = 0; j < 4; j++) acc[i][j] = (i32x4){0, 0, 0, 0};

    // staging: wave covers dh = wid&1, cg pair = (wid>>1)*2 + {0,1}
    const int sdh = wid & 1;
    const int scg = (wid >> 1) * 2;
    const u8* gbase = xq + (size_t)(b * PH + h0 + sdh) * 9216 + lane * 16;
    // weights: lane base for o-row (wo*64 + i*16 + lrow), k-chunk quad*16
    const u8* wl = Bw + (size_t)(o_blk + wo * 64 + lrow) * 64 + quad * 16;

    for (int r = 0; r < 9; ++r) {
        const int kh = r / 3, kw = r % 3;
#pragma unroll
        for (int q = 0; q < 2; ++q) {
            const int st = r * 2 + q;
            __syncthreads();
#pragma unroll
            for (int cc = 0; cc < 2; ++cc) {
                const int cg = scg + cc;
                const u8* src = gbase + (size_t)kh * 9216 + (q * 4 + cg) * (PW * 16) + kw * 16;
                glds16(src, &Is[cg][sdh * 64][0]);
            }
            i32x4 af[4];
#pragma unroll
            for (int i = 0; i < 4; ++i)
                af[i] = *(const i32x4*)(wl + ((size_t)st * 256 + i * 16) * 64);
            __syncthreads();
            i32x4 bfr[4];
#pragma unroll
            for (int j = 0; j < 4; ++j)
                bfr[j] = *(const i32x4*)&Is[quad][wm * 64 + j * 16 + lrow][0];
#pragma unroll
            for (int i = 0; i < 4; ++i)
#pragma unroll
                for (int j = 0; j < 4; ++j)
                    acc[i][j] = __builtin_amdgcn_mfma_i32_16x16x64_i8(af[i], bfr[j], acc[i][j], 0, 0, 0);
        }
    }

    // ---- epilogue: D[row=o][col=m]; col=lane&15, row=quad*4+reg ----
    const int hh = h0 + wm;
    int sa_j[4];
#pragma unroll
    for (int j = 0; j < 4; ++j) {
        const int w = j * 16 + lrow;
        sa_j[j] = (w < HW) ? Sa[(b * HW + hh) * 64 + w] : 0;
    }
#pragma unroll
    for (int i = 0; i < 4; i++) {
        const int obase = o_blk + wo * 64 + i * 16 + quad * 4;
#pragma unroll
        for (int rg = 0; rg < 4; ++rg) {
            const int o = obase + rg;
            const int wsum = Wsum[o];
            const float bs = bias[o];
#pragma unroll
            for (int j = 0; j < 4; ++j) {
                const int w = j * 16 + lrow;
                if (w < HW) {
                    int tot = acc[i][j][rg] + 128 * (sa_j[j] + wsum) + 18874368;
                    out[(((size_t)b * O_CH + o) * HW + hh) * HW + w] = (float)tot + bs;
                }
            }
        }
    }
}

extern "C" void kernel_launch(void* const* d_in, const int* in_sizes, int n_in,
                              void* d_out, int out_size, void* d_ws, size_t ws_size,
                              hipStream_t stream) {
    const float* x     = (const float*)d_in[0];
    const float* pcilt = (const float*)d_in[1];
    const float* bias  = (const float*)d_in[2];
    float* out = (float*)d_out;

    u8* ws = (u8*)d_ws;
    u8*  xq   = ws + XQ_OFF;
    u8*  Bw   = ws + BW_OFF;
    int* Tc   = (int*)(ws + TC_OFF);
    int* Sa   = (int*)(ws + SA_OFF);
    int* Wsum = (int*)(ws + WS_OFF);

    quant_pad<<<dim3(PH, B_N), 256, 0, stream>>>(x, xq, Tc, Wsum);
    make_w<<<484, 256, 0, stream>>>(pcilt, Bw, Tc, Sa, Wsum);
    conv_mfma<<<dim3(O_CH / 128, HW / 2, B_N), dim3(256), 0, stream>>>(xq, Bw, Sa, Wsum, bias, out);
}

// Round 7
// 404.486 us; speedup vs baseline: 1.0554x; 1.0042x over previous
//
#include <hip/hip_runtime.h>
#include <stdint.h>

typedef unsigned char u8;
typedef unsigned short u16;
typedef int i32x4 __attribute__((ext_vector_type(4)));
typedef u8 u8x4 __attribute__((ext_vector_type(4)));

#define B_N   16
#define C_CH  128
#define O_CH  256
#define HW    56
#define PH    58
#define PW    72

#define GLOBAL_AS __attribute__((address_space(1)))
#define LDS_AS    __attribute__((address_space(3)))

__device__ __forceinline__ void glds16(const void* g, void* l) {
    __builtin_amdgcn_global_load_lds((const GLOBAL_AS void*)g, (LDS_AS void*)l, 16, 0, 0);
}

// ws layout (bytes)
#define XQ_OFF   0                       // u8 [16][58][8 cg][72 wp][16 c]  = 8,552,448
#define BW_OFF   8552448                 // u8 [18 st][256 o][64 c]         =   294,912
#define TC_OFF   (BW_OFF + 294912)       // int [16][58][72]                =   267,264
#define WS_OFF   (TC_OFF + 267264)       // int [256]

// ---------------------------------------------------------------------------
// fused prep:
//  blocks [0,928):    quantize + pad + NCHW->[b][hp][cg][wp][c16] as shifted
//                     i8 (q^0x80 == q-128; pad = -128), plus channel-sum plane
//                     Tc[b][hp][wp] = sum_c (q-128).
//  blocks [928,1216): Bw[st=r*2+q][o][c64] = (u8)qw ^ 0x80 and
//                     Wsum[o] += sum(qw-128)  (Wsum pre-zeroed by memset).
// ---------------------------------------------------------------------------
__global__ __launch_bounds__(256) void prep(const float* __restrict__ x,
                                            const float* __restrict__ pcilt,
                                            u8* __restrict__ xq,
                                            u8* __restrict__ Bw,
                                            int* __restrict__ Tc,
                                            int* __restrict__ Wsum) {
    const int bx = blockIdx.x;
    const int tid = threadIdx.x;

    if (bx < PH * B_N) {
        __shared__ u16 Lt[C_CH][57];             // integer q in [0,255]
        const int hp = bx % PH;
        const int b = bx / PH;
        const int h = hp - 1;
        const bool interior = (unsigned)h < HW;

        if (interior) {
            const float* xr = x + ((size_t)b * C_CH * HW + h) * HW;
            for (int i = 0; i < 7; ++i) {        // 1792 float4 units = 128c x 14
                int u = i * 256 + tid;
                int c = u / 14, w4 = u % 14;
                float4 v = *(const float4*)(xr + (size_t)c * (HW * HW) + w4 * 4);
                Lt[c][w4 * 4 + 0] = (u16)(int)fminf(fmaxf(rintf(v.x * 255.0f), 0.0f), 255.0f);
                Lt[c][w4 * 4 + 1] = (u16)(int)fminf(fmaxf(rintf(v.y * 255.0f), 0.0f), 255.0f);
                Lt[c][w4 * 4 + 2] = (u16)(int)fminf(fmaxf(rintf(v.z * 255.0f), 0.0f), 255.0f);
                Lt[c][w4 * 4 + 3] = (u16)(int)fminf(fmaxf(rintf(v.w * 255.0f), 0.0f), 255.0f);
            }
        }
        __syncthreads();
        // write xq row for (b,hp): 8 cg x 72 wp x 16 c = 9216 B = 2304 dwords
        u8* dst = xq + (size_t)(b * PH + hp) * 9216;
        for (int j = 0; j < 9; ++j) {
            int u = j * 256 + tid;
            int d4 = u & 3;
            int wp = (u >> 2) % PW;
            int cg = u / (4 * PW);
            int w = wp - 1;
            u8x4 v;
            if (interior && (unsigned)w < HW) {
#pragma unroll
                for (int e = 0; e < 4; ++e)
                    v[e] = (u8)Lt[cg * 16 + d4 * 4 + e][w] ^ 0x80;
            } else {
                v = (u8x4){0x80, 0x80, 0x80, 0x80};
            }
            *(u8x4*)(dst + (size_t)u * 4) = v;
        }
        // channel-sum plane
        if (tid < PW) {
            int wp = tid, w = wp - 1;
            int s = -128 * C_CH;
            if (interior && (unsigned)w < HW) {
                for (int c = 0; c < C_CH; ++c) s += (int)Lt[c][w];
            }
            Tc[(b * PH + hp) * PW + wp] = s;
        }
    } else {
        int v = (bx - PH * B_N) * 256 + tid;     // 73728 dword units
        int cb4 = v & 15;
        int o   = (v >> 4) & 255;
        int q   = (v >> 12) & 1;
        int r   = v >> 13;
        u8x4 out4;
        int part = 0;
#pragma unroll
        for (int e = 0; e < 4; ++e) {
            int c = q * 64 + cb4 * 4 + e;
            float w = pcilt[((size_t)(o * C_CH + c) * 9 + r) * 256 + 1];
            int qi = (int)w;
            out4[e] = (u8)qi ^ 0x80;
            part += qi - 128;
        }
        *(u8x4*)(Bw + (size_t)v * 4) = out4;
        part += __shfl_down(part, 1);
        part += __shfl_down(part, 2);
        part += __shfl_down(part, 4);
        part += __shfl_down(part, 8);
        if ((tid & 15) == 0) atomicAdd(&Wsum[o], part);
    }
}

// ---------------------------------------------------------------------------
// conv as implicit GEMM, exact i8 (zero-point shifted):
//   ACC[o][m] = sum_k (w-128)(a-128)
//   out = ACC + 128*(Sa[m] + Wsum[o]) + 128^2*1152 + bias
// Sa (3x3 box of Tc for this block's 2 output rows) computed in the prologue
// into 512 B LDS. 18 stages of K=64; Is = 8 KB LDS; weights direct from L2.
// ---------------------------------------------------------------------------
__global__ __launch_bounds__(256) void conv_mfma(const u8* __restrict__ xq,
                                                 const u8* __restrict__ Bw,
                                                 const int* __restrict__ Tc,
                                                 const int* __restrict__ Wsum,
                                                 const float* __restrict__ bias,
                                                 float* __restrict__ out) {
    __shared__ __align__(16) u8 Is[4][128][16];   // [cg16][m][c16]  8 KB
    __shared__ int Sa_l[2][64];                   // 512 B

    const int tid = threadIdx.x;
    const int o_blk = blockIdx.x * 128;
    const int h0 = blockIdx.y * 2;
    const int b = blockIdx.z;

    const int lane = tid & 63;
    const int wid = tid >> 6;
    const int wo = wid & 1;
    const int wm = wid >> 1;
    const int quad = lane >> 4;
    const int lrow = lane & 15;

    // ---- prologue: per-block Sa (activation zero-point correction) ----
    if (tid < 128) {
        const int rr = tid >> 6, w = tid & 63;
        int s = 0;
        if (w < HW) {
            const int* t = Tc + (b * PH + h0 + rr) * PW + w;
#pragma unroll
            for (int dh = 0; dh < 3; ++dh)
#pragma unroll
                for (int dw = 0; dw < 3; ++dw)
                    s += t[dh * PW + dw];
        }
        Sa_l[rr][w] = s;
    }

    i32x4 acc[4][4];
#pragma unroll
    for (int i = 0; i < 4; i++)
#pragma unroll
        for (int j = 0; j < 4; j++) acc[i][j] = (i32x4){0, 0, 0, 0};

    // staging: wave covers dh = wid&1, cg pair = (wid>>1)*2 + {0,1}
    const int sdh = wid & 1;
    const int scg = (wid >> 1) * 2;
    const u8* gbase = xq + (size_t)(b * PH + h0 + sdh) * 9216 + lane * 16;
    const u8* wl = Bw + (size_t)(o_blk + wo * 64 + lrow) * 64 + quad * 16;

    for (int r = 0; r < 9; ++r) {
        const int kh = r / 3, kw = r % 3;
#pragma unroll
        for (int q = 0; q < 2; ++q) {
            const int st = r * 2 + q;
            __syncthreads();
#pragma unroll
            for (int cc = 0; cc < 2; ++cc) {
                const int cg = scg + cc;
                const u8* src = gbase + (size_t)kh * 9216 + (q * 4 + cg) * (PW * 16) + kw * 16;
                glds16(src, &Is[cg][sdh * 64][0]);
            }
            i32x4 af[4];
#pragma unroll
            for (int i = 0; i < 4; ++i)
                af[i] = *(const i32x4*)(wl + ((size_t)st * 256 + i * 16) * 64);
            __syncthreads();
            i32x4 bfr[4];
#pragma unroll
            for (int j = 0; j < 4; ++j)
                bfr[j] = *(const i32x4*)&Is[quad][wm * 64 + j * 16 + lrow][0];
#pragma unroll
            for (int i = 0; i < 4; ++i)
#pragma unroll
                for (int j = 0; j < 4; ++j)
                    acc[i][j] = __builtin_amdgcn_mfma_i32_16x16x64_i8(af[i], bfr[j], acc[i][j], 0, 0, 0);
        }
    }

    // ---- epilogue: D[row=o][col=m]; col=lane&15, row=quad*4+reg ----
    const int hh = h0 + wm;
    int sa_j[4];
#pragma unroll
    for (int j = 0; j < 4; ++j) {
        const int w = j * 16 + lrow;
        sa_j[j] = (w < HW) ? Sa_l[wm][w] : 0;
    }
#pragma unroll
    for (int i = 0; i < 4; i++) {
        const int obase = o_blk + wo * 64 + i * 16 + quad * 4;
#pragma unroll
        for (int rg = 0; rg < 4; ++rg) {
            const int o = obase + rg;
            const int wsum = Wsum[o];
            const float bs = bias[o];
#pragma unroll
            for (int j = 0; j < 4; ++j) {
                const int w = j * 16 + lrow;
                if (w < HW) {
                    int tot = acc[i][j][rg] + 128 * (sa_j[j] + wsum) + 18874368;
                    out[(((size_t)b * O_CH + o) * HW + hh) * HW + w] = (float)tot + bs;
                }
            }
        }
    }
}

extern "C" void kernel_launch(void* const* d_in, const int* in_sizes, int n_in,
                              void* d_out, int out_size, void* d_ws, size_t ws_size,
                              hipStream_t stream) {
    const float* x     = (const float*)d_in[0];
    const float* pcilt = (const float*)d_in[1];
    const float* bias  = (const float*)d_in[2];
    float* out = (float*)d_out;

    u8* ws = (u8*)d_ws;
    u8*  xq   = ws + XQ_OFF;
    u8*  Bw   = ws + BW_OFF;
    int* Tc   = (int*)(ws + TC_OFF);
    int* Wsum = (int*)(ws + WS_OFF);

    hipMemsetAsync(Wsum, 0, O_CH * sizeof(int), stream);
    prep<<<PH * B_N + 288, 256, 0, stream>>>(x, pcilt, xq, Bw, Tc, Wsum);
    conv_mfma<<<dim3(O_CH / 128, HW / 2, B_N), dim3(256), 0, stream>>>(xq, Bw, Tc, Wsum, bias, out);
}